// Round 9
// baseline (290.562 us; speedup 1.0000x reference)
//
#include <hip/hip_runtime.h>

typedef __attribute__((ext_vector_type(8))) short short8;
typedef __attribute__((ext_vector_type(4))) float f32x4;

#define SS 2048
#define HH 16
#define NOPE_D 128
#define ROPE_D 64
#define VDIM 128
#define QD 192
#define SCALE_F 0.07216878364870323f       // 1/sqrt(192)
#define LOG2E 1.4426950408889634f

__device__ __forceinline__ unsigned short f2bf(float f) {
    unsigned int x = __builtin_bit_cast(unsigned int, f);
    unsigned int r = (x + 0x7fffu + ((x >> 16) & 1u)) >> 16;
    return (unsigned short)r;
}
__device__ __forceinline__ float bf2f(unsigned short u) {
    return __builtin_bit_cast(float, (unsigned int)u << 16);
}

#define GLDS16(g, l) __builtin_amdgcn_global_load_lds( \
    (const __attribute__((address_space(1))) void*)(g), \
    (__attribute__((address_space(3))) void*)(l), 16, 0, 0)

// ------- fused f32->bf16 convert (4 arrays) + rope_k, one launch -------
__global__ __launch_bounds__(256) void cvt_all(
    const float* __restrict__ Q, const float* __restrict__ WUQ,
    const float* __restrict__ KV, const float* __restrict__ WUKV,
    const float* __restrict__ PE, const float* __restrict__ cs, const float* __restrict__ sn,
    unsigned short* __restrict__ Qb, unsigned short* __restrict__ WUQb,
    unsigned short* __restrict__ KVb, unsigned short* __restrict__ WUKVb,
    unsigned short* __restrict__ kpe)
{
    int bid = blockIdx.x;
    if (bid >= 14848) {   // rope_k: PE (4096x64) -> kpe bf16
        int idx = (bid - 14848) * 256 + threadIdx.x;
        int i = idx & 31, row = idx >> 5;
        float x1 = PE[row * 64 + i], x2 = PE[row * 64 + 32 + i];
        float c1 = cs[row * 64 + i],      s1 = sn[row * 64 + i];
        float c2 = cs[row * 64 + 32 + i], s2 = sn[row * 64 + 32 + i];
        kpe[row * 64 + i]      = f2bf(x1 * c1 - x2 * s1);
        kpe[row * 64 + 32 + i] = f2bf(x2 * c2 + x1 * s2);
        return;
    }
    const float* src; unsigned short* dst; float scale = 1.0f;
    if (bid < 6144)       { src = Q;    dst = Qb; }
    else if (bid < 10752) { src = WUQ;  dst = WUQb; bid -= 6144; scale = SCALE_F * LOG2E; }
    else if (bid < 12800) { src = KV;   dst = KVb;  bid -= 10752; }
    else                  { src = WUKV; dst = WUKVb; bid -= 12800; }
    int i = (bid * 256 + threadIdx.x) * 4;
    float4 v = *(const float4*)(src + i);
    ushort4 o = { f2bf(v.x * scale), f2bf(v.y * scale), f2bf(v.z * scale), f2bf(v.w * scale) };
    *(ushort4*)(dst + i) = o;
}

// ------- fused GEMM1+GEMM2, 128x128 tile, BK=64, XOR-swizzled LDS -------
__global__ __launch_bounds__(256) void gemm_fused(
    const unsigned short* __restrict__ Qb, const unsigned short* __restrict__ WUQb,
    const unsigned short* __restrict__ KVb, const unsigned short* __restrict__ WUKVb,
    unsigned short* __restrict__ qbuf, unsigned short* __restrict__ knope,
    unsigned short* __restrict__ vT,
    const float* __restrict__ cs, const float* __restrict__ sn)
{
    __shared__ unsigned short As[128 * 64];
    __shared__ unsigned short Bs[128 * 64];
    const int t = threadIdx.x, w = t >> 6, lane = t & 63;
    const int n16 = lane & 15, quad = lane >> 4;

    int bid = blockIdx.x;
    const unsigned short *A, *B; int N, K, bm, bn; bool g1;
    if (bid < 768) { g1 = true;  A = Qb;  B = WUQb;  N = 3072; K = 1536;
                     bm = (bid / 24) * 128; bn = (bid % 24) * 128; }
    else           { g1 = false; bid -= 768; A = KVb; B = WUKVb; N = 4096; K = 512;
                     bm = (bid / 32) * 128; bn = (bid % 32) * 128; }

    const int wm = (w >> 1) * 64, wn = (w & 1) * 64;
    f32x4 acc[4][4] = {};

    const int lr = lane >> 3, lc = lane & 7;
    const int sw = (lc ^ lr) * 8;           // swizzled source chunk
    const unsigned short* gA = A + (size_t)(bm + w * 32 + lr) * K + sw;
    const unsigned short* gB = B + (size_t)(bn + w * 32 + lr) * K + sw;

    for (int k0 = 0; k0 < K; k0 += 64) {
        __syncthreads();
        for (int j = 0; j < 4; j++) {
            GLDS16(gA + (size_t)j * 8 * K + k0, &As[(w * 32 + j * 8) * 64]);
            GLDS16(gB + (size_t)j * 8 * K + k0, &Bs[(w * 32 + j * 8) * 64]);
        }
        __syncthreads();
        for (int ks = 0; ks < 2; ks++) {
            short8 af[4], bf[4];
            for (int mt = 0; mt < 4; mt++) {
                int rw = wm + mt * 16 + n16;
                af[mt] = *(const short8*)&As[rw * 64 + (((ks * 4 + quad) ^ (rw & 7)) * 8)];
            }
            for (int nt = 0; nt < 4; nt++) {
                int rw = wn + nt * 16 + n16;
                bf[nt] = *(const short8*)&Bs[rw * 64 + (((ks * 4 + quad) ^ (rw & 7)) * 8)];
            }
            for (int mt = 0; mt < 4; mt++)
                for (int nt = 0; nt < 4; nt++)
                    acc[mt][nt] = __builtin_amdgcn_mfma_f32_16x16x32_bf16(af[mt], bf[nt], acc[mt][nt], 0, 0, 0);
        }
    }

    const int colbase = bn + wn;
    if (g1) {
        const bool is_pe = ((colbase % 192) >= 128);
        if (is_pe) {
            for (int mt = 0; mt < 4; mt++)
                for (int r = 0; r < 4; r++) {
                    int row = bm + wm + mt * 16 + quad * 4 + r;
                    const float* cr = cs + row * 64;
                    const float* sr = sn + row * 64;
                    for (int nt = 0; nt < 2; nt++) {
                        int i = nt * 16 + n16;
                        float x1 = acc[mt][nt][r], x2 = acc[mt][nt + 2][r];
                        float o1 = x1 * cr[i] - x2 * sr[i];
                        float o2 = x2 * cr[32 + i] + x1 * sr[32 + i];
                        qbuf[(size_t)row * N + colbase + i] = f2bf(o1);
                        qbuf[(size_t)row * N + colbase + 32 + i] = f2bf(o2);
                    }
                }
        } else {
            for (int mt = 0; mt < 4; mt++)
                for (int nt = 0; nt < 4; nt++)
                    for (int r = 0; r < 4; r++)
                        qbuf[(size_t)(bm + wm + mt * 16 + quad * 4 + r) * N + colbase + nt * 16 + n16]
                            = f2bf(acc[mt][nt][r]);
        }
    } else {
        if ((colbase & 255) < 128) {
            for (int mt = 0; mt < 4; mt++)
                for (int nt = 0; nt < 4; nt++) {
                    int col = colbase + nt * 16 + n16;
                    int h = col >> 8, d = col & 255;
                    for (int r = 0; r < 4; r++)
                        knope[(size_t)(bm + wm + mt * 16 + quad * 4 + r) * 2048 + h * 128 + d]
                            = f2bf(acc[mt][nt][r]);
                }
        } else {
            for (int mt = 0; mt < 4; mt++)
                for (int nt = 0; nt < 4; nt++) {
                    int col = colbase + nt * 16 + n16;
                    int h = col >> 8, vd = (col & 255) - 128;
                    int row0 = bm + wm + mt * 16 + quad * 4;
                    int b = row0 >> 11, s0 = row0 & 2047;
                    // key permutation pi within 64-groups (PV A/B pairing order)
                    int l6 = s0 & 63;
                    int scol = (s0 & ~63) + ((l6 >> 5) & 1) * 32 + ((l6 >> 2) & 3) * 8
                             + ((l6 >> 4) & 1) * 4 + (l6 & 3);
                    ushort4 pk = { f2bf(acc[mt][nt][0]), f2bf(acc[mt][nt][1]),
                                   f2bf(acc[mt][nt][2]), f2bf(acc[mt][nt][3]) };
                    *(ushort4*)&vT[((size_t)(b * 16 + h) * 128 + vd) * 2048 + scol] = pk;
                }
        }
    }
}

// ------- flash attention, split-K partial pass, QBLK=256 / 8 waves -------
// v10: QBLK 128 -> 256 with 512-thread blocks. Each staged K/V tile (40KB)
// now feeds 8 waves x 32 q-rows = 256 rows -> total tile instances drop
// 8704 -> 4608 (staged L2/L3 bytes x0.53) at identical MFMA count. Per-wave
// state/inner loop = R8 verbatim (32 rows, same softmax/T13/msub; pipeline
// variants all regressed, inner stays single-buffered).
// Split-K (equal spans): block j = qtA*32+cc runs
//   segA = lo(qt=qtA):   k-tiles [0, 2qt+2)
//   segB = hi(qt=7-qtA): k-tiles [2qt+2, 4qt+4)
// -> every block exactly 18 tiles; 256 blocks ~ 1/CU. Causal mask: kt>=4qt.
// Partials unnormalized: hi -> f32 out; lo -> bf16 dead Qb/WUQb; (m,l) ->
// dead KVb/WUKVb. attn_combine merges.
__global__ __launch_bounds__(512, 2) void attn_part(
    const unsigned short* __restrict__ qbuf,   // (4096, 3072) roped, pre-scaled
    const unsigned short* __restrict__ knope,  // (4096, 2048): [row][h*128+d]
    const unsigned short* __restrict__ kpe,    // (4096, 64) roped
    const unsigned short* __restrict__ vT,     // [(b*16+h)*128+vd][pi(s)]
    float* __restrict__ out,                   // (B,S,H,128) f32 (raw hi partial)
    unsigned short* __restrict__ OloB,         // [256][256][128] bf16 lo partial
    float2* __restrict__ mlLo,                 // [256][256] {m,l} lo
    float2* __restrict__ mlHi)                 // [256][256] {m,l} hi
{
    const int t = threadIdx.x, w = t >> 6, lane = t & 63;
    const int n16 = lane & 15, quad = lane >> 4;

    __shared__ unsigned short Kn[64 * 128];
    __shared__ unsigned short Kp[64 * 64];
    __shared__ unsigned short Vt[128 * 64];
    __shared__ float Al[8][32];

    const int j = blockIdx.x;
    const int qtA = j >> 5, cc = j & 31;
    const int h = cc & 15, b = cc >> 4;

    const unsigned short* knb = knope + (size_t)b * 2048 * 2048 + h * 128;
    const unsigned short* kpb = kpe + (size_t)b * 2048 * 64;
    const unsigned short* vtb = vT + (size_t)(b * 16 + h) * 128 * 2048;

    for (int seg = 0; seg < 2; ++seg) {
        const int qt    = seg ? (7 - qtA) : qtA;
        const int ktbeg = seg ? (2 * qt + 2) : 0;
        const int ktend = seg ? (4 * qt + 4) : (2 * qt + 2);
        const int uid   = qt * 32 + cc;

        // Q as B-frags: wave w covers q rows qt*256 + w*32 + qg*16 + n16
        short8 qf[2][6];
        for (int qg = 0; qg < 2; qg++) {
            size_t grow = (size_t)(b * SS + qt * 256 + w * 32 + qg * 16 + n16);
            const unsigned short* qp = qbuf + grow * (HH * QD) + h * QD + quad * 8;
            for (int ks = 0; ks < 6; ks++) qf[qg][ks] = *(const short8*)(qp + ks * 32);
        }

        f32x4 O[2][8] = {};
        float m_i[2] = { -INFINITY, -INFINITY };
        float l_i[2] = { 0.f, 0.f };

        for (int kt = ktbeg; kt < ktend; kt++) {
            __syncthreads();
            {   // K nope: 64 keys x 128 shorts; 8 waves x 2 glds x 4 rows
                int r = w * 8 + (lane >> 4);
                int sl = lane & 15;
                for (int jj = 0; jj < 2; jj++) {
                    int rr = r + jj * 4;
                    const unsigned short* g = knb + (size_t)(kt * 64 + rr) * 2048 + ((sl ^ (rr & 7)) * 8);
                    GLDS16(g, &Kn[(w * 8 + jj * 4) * 128]);
                }
            }
            {   // K pe: 64 keys x 64 shorts; 8 waves x 1 gld x 8 rows
                int rr = w * 8 + (lane >> 3);
                int sl = lane & 7;
                const unsigned short* g = kpb + (size_t)(kt * 64 + rr) * 64 + ((sl ^ (rr & 7)) * 8);
                GLDS16(g, &Kp[(w * 8) * 64]);
            }
            {   // V^T: 128 vd x 64 keys (key-permuted); 8 waves x 2 glds x 8 rows
                int r = w * 16 + (lane >> 3);
                int sl = lane & 7;
                for (int jj = 0; jj < 2; jj++) {
                    int rr = r + jj * 8;
                    const unsigned short* g = vtb + (size_t)rr * 2048 + kt * 64 + ((sl ^ (rr & 7)) * 8);
                    GLDS16(g, &Vt[(w * 16 + jj * 8) * 64]);
                }
            }
            __syncthreads();

            // S^T[key][q]: A = K-frags (LDS, shared across qg), B = Q (regs)
            f32x4 Sg[2][4];
            for (int nt = 0; nt < 4; nt++) {
                int key = nt * 16 + n16, kx = key & 7;
                f32x4 a0 = {}, a1 = {};
                for (int ks = 0; ks < 4; ks++) {
                    short8 af = *(const short8*)&Kn[key * 128 + (((ks * 4 + quad) ^ kx) * 8)];
                    a0 = __builtin_amdgcn_mfma_f32_16x16x32_bf16(af, qf[0][ks], a0, 0, 0, 0);
                    a1 = __builtin_amdgcn_mfma_f32_16x16x32_bf16(af, qf[1][ks], a1, 0, 0, 0);
                }
                for (int ks = 0; ks < 2; ks++) {
                    short8 af = *(const short8*)&Kp[key * 64 + (((ks * 4 + quad) ^ kx) * 8)];
                    a0 = __builtin_amdgcn_mfma_f32_16x16x32_bf16(af, qf[0][4 + ks], a0, 0, 0, 0);
                    a1 = __builtin_amdgcn_mfma_f32_16x16x32_bf16(af, qf[1][4 + ks], a1, 0, 0, 0);
                }
                Sg[0][nt] = a0; Sg[1][nt] = a1;
            }

            if (kt >= 4 * qt) {   // causal mask: tiles overlapping/above diagonal
                for (int qg = 0; qg < 2; qg++) {
                    int qq = qt * 256 + w * 32 + qg * 16 + n16;
                    for (int nt = 0; nt < 4; nt++) {
                        int key0 = kt * 64 + nt * 16 + quad * 4;
                        for (int r = 0; r < 4; r++)
                            if (key0 + r > qq) Sg[qg][nt][r] = -INFINITY;
                    }
                }
            }

            // online softmax (base 2), T13 defer-max, msub guard for dead rows
            float alpha[2];
            bool skipq[2];
            for (int qg = 0; qg < 2; qg++) {
                float mx = -INFINITY;
                for (int nt = 0; nt < 4; nt++)
                    for (int r = 0; r < 4; r++) mx = fmaxf(mx, Sg[qg][nt][r]);
                mx = fmaxf(mx, __shfl_xor(mx, 16, 64));
                mx = fmaxf(mx, __shfl_xor(mx, 32, 64));
                const bool skip = __all(mx <= m_i[qg] + 8.0f);
                skipq[qg] = skip;
                float mnew = skip ? m_i[qg] : fmaxf(m_i[qg], mx);
                alpha[qg] = skip ? 1.0f : exp2f(m_i[qg] - mnew);
                m_i[qg] = mnew;
                const float msub = (mnew == -INFINITY) ? 0.0f : mnew;
                float rs = 0.f;
                for (int nt = 0; nt < 4; nt++)
                    for (int r = 0; r < 4; r++) {
                        float pv = exp2f(Sg[qg][nt][r] - msub);
                        Sg[qg][nt][r] = pv;
                        rs += pv;
                    }
                l_i[qg] = l_i[qg] * alpha[qg] + rs;   // per-lane partial (quad-split)
            }
            // broadcast alpha (S^T q=n16 domain) to O lanes (q=quad*4+r domain)
            if (quad == 0) { Al[w][n16] = alpha[0]; Al[w][16 + n16] = alpha[1]; }
            if (!skipq[0]) {
                f32x4 av0 = *(const f32x4*)&Al[w][quad * 4];
                for (int v8 = 0; v8 < 8; v8++)
                    for (int r = 0; r < 4; r++) O[0][v8][r] *= av0[r];
            }
            if (!skipq[1]) {
                f32x4 av1 = *(const f32x4*)&Al[w][16 + quad * 4];
                for (int v8 = 0; v8 < 8; v8++)
                    for (int r = 0; r < 4; r++) O[1][v8][r] *= av1[r];
            }

            // pack P to bf16 A-frags (k order matches pi-permuted V columns)
            short8 pp[2][2];
            for (int qg = 0; qg < 2; qg++)
                for (int ntp = 0; ntp < 2; ntp++) {
                    short8 pa;
                    for (int jj = 0; jj < 4; jj++) pa[jj] = (short)f2bf(Sg[qg][ntp * 2][jj]);
                    for (int jj = 0; jj < 4; jj++) pa[4 + jj] = (short)f2bf(Sg[qg][ntp * 2 + 1][jj]);
                    pp[qg][ntp] = pa;
                }
            // PV: O[q][vd] += P * V, B-frags shared across qg
            for (int ntp = 0; ntp < 2; ntp++)
                for (int v8 = 0; v8 < 8; v8++) {
                    int vd = v8 * 16 + n16;
                    short8 vb = *(const short8*)&Vt[vd * 64 + (((ntp * 4 + quad) ^ (vd & 7)) * 8)];
                    O[0][v8] = __builtin_amdgcn_mfma_f32_16x16x32_bf16(pp[0][ntp], vb, O[0][v8], 0, 0, 0);
                    O[1][v8] = __builtin_amdgcn_mfma_f32_16x16x32_bf16(pp[1][ntp], vb, O[1][v8], 0, 0, 0);
                }
        }

        // epilogue: total l per row (reduce across quads); store RAW partials
        float l0 = l_i[0];
        l0 += __shfl_xor(l0, 16, 64); l0 += __shfl_xor(l0, 32, 64);
        float l1 = l_i[1];
        l1 += __shfl_xor(l1, 16, 64); l1 += __shfl_xor(l1, 32, 64);

        if (seg == 0) {
            unsigned short* lb = OloB + (size_t)uid * 256 * 128;
            for (int qg = 0; qg < 2; qg++)
                for (int r = 0; r < 4; r++) {
                    int row = w * 32 + qg * 16 + quad * 4 + r;
                    unsigned short* lp = lb + (size_t)row * 128;
                    for (int v8 = 0; v8 < 8; v8++)
                        lp[v8 * 16 + n16] = f2bf(O[qg][v8][r]);
                }
            if (quad == 0) {
                mlLo[uid * 256 + w * 32 + n16]      = make_float2(m_i[0], l0);
                mlLo[uid * 256 + w * 32 + 16 + n16] = make_float2(m_i[1], l1);
            }
        } else {
            for (int qg = 0; qg < 2; qg++)
                for (int r = 0; r < 4; r++) {
                    size_t qrow = (size_t)(b * SS + qt * 256 + w * 32 + qg * 16 + quad * 4 + r);
                    float* op = out + (qrow * HH + h) * VDIM;
                    for (int v8 = 0; v8 < 8; v8++)
                        op[v8 * 16 + n16] = O[qg][v8][r];
                }
            if (quad == 0) {
                mlHi[uid * 256 + w * 32 + n16]      = make_float2(m_i[0], l0);
                mlHi[uid * 256 + w * 32 + 16 + n16] = make_float2(m_i[1], l1);
            }
        }
    }
}

// ------- combine: out = (a_lo*O_lo + a_hi*O_hi) / (a_lo*l_lo + a_hi*l_hi) ----
__global__ __launch_bounds__(256) void attn_combine(
    const unsigned short* __restrict__ OloB,
    const float2* __restrict__ mlLo, const float2* __restrict__ mlHi,
    float* __restrict__ out)
{
    int idx = blockIdx.x * 256 + threadIdx.x;   // 256*256*16 threads, 8 vd each
    int vd8 = idx & 15;
    int rowg = idx >> 4;                         // uid*256 + row
    int uid = rowg >> 8, row = rowg & 255;
    int qt = uid >> 5, cc = uid & 31, h = cc & 15, b = cc >> 4;

    float2 lo = mlLo[rowg], hi = mlHi[rowg];
    float m  = fmaxf(lo.x, hi.x);                 // lo.x always finite
    float al = exp2f(lo.x - m);
    float ah = exp2f(hi.x - m);                   // hi.x=-INF -> 0, no NaN
    float rl = 1.f / (lo.y * al + hi.y * ah);
    al *= rl; ah *= rl;

    const unsigned short* lp = OloB + (size_t)rowg * 128 + vd8 * 8;
    float* op = out + ((size_t)(b * SS + qt * 256 + row) * HH + h) * VDIM + vd8 * 8;

    ushort4 u0 = *(const ushort4*)lp;
    ushort4 u1 = *(const ushort4*)(lp + 4);
    float4 h0 = *(const float4*)op;
    float4 h1 = *(const float4*)(op + 4);
    float4 o0, o1;
    o0.x = bf2f(u0.x) * al + h0.x * ah;
    o0.y = bf2f(u0.y) * al + h0.y * ah;
    o0.z = bf2f(u0.z) * al + h0.z * ah;
    o0.w = bf2f(u0.w) * al + h0.w * ah;
    o1.x = bf2f(u1.x) * al + h1.x * ah;
    o1.y = bf2f(u1.y) * al + h1.y * ah;
    o1.z = bf2f(u1.z) * al + h1.z * ah;
    o1.w = bf2f(u1.w) * al + h1.w * ah;
    *(float4*)op = o0;
    *(float4*)(op + 4) = o1;
}

extern "C" void kernel_launch(void* const* d_in, const int* in_sizes, int n_in,
                              void* d_out, int out_size, void* d_ws, size_t ws_size,
                              hipStream_t stream) {
    const float* Q    = (const float*)d_in[0];
    const float* KV   = (const float*)d_in[1];
    const float* PE   = (const float*)d_in[2];
    const float* WUQ  = (const float*)d_in[3];
    const float* WUKV = (const float*)d_in[4];
    const float* cosp = (const float*)d_in[5];
    const float* sinp = (const float*)d_in[6];
    float* out = (float*)d_out;

    unsigned short* qbuf  = (unsigned short*)d_ws;                 // 4096x3072
    unsigned short* knope = qbuf  + (size_t)4096 * 3072;           // 4096x2048
    unsigned short* vT    = knope + (size_t)4096 * 2048;           // 4096x2048 (pi-permuted)
    unsigned short* kpe   = vT    + (size_t)4096 * 2048;           // 4096x64
    unsigned short* Qb    = kpe   + (size_t)4096 * 64;             // 4096x1536
    unsigned short* WUQb  = Qb    + (size_t)4096 * 1536;           // 3072x1536
    unsigned short* KVb   = WUQb  + (size_t)3072 * 1536;           // 4096x512
    unsigned short* WUKVb = KVb   + (size_t)4096 * 512;            // 4096x512

    // split-K partial buffers, overlaid on regions dead after gemm_fused:
    unsigned short* OloB = Qb;                 // 256*256*128 bf16 = 16.8 MB (<= Qb+WUQb)
    float2* mlLo = (float2*)KVb;               // 256*256*8B = 0.5 MB
    float2* mlHi = (float2*)WUKVb;             // 256*256*8B = 0.5 MB

    cvt_all<<<15360, 256, 0, stream>>>(Q, WUQ, KV, WUKV, PE, cosp, sinp,
                                       Qb, WUQb, KVb, WUKVb, kpe);
    gemm_fused<<<1792, 256, 0, stream>>>(Qb, WUQb, KVb, WUKVb,
                                         qbuf, knope, vT, cosp, sinp);
    attn_part<<<256, 512, 0, stream>>>(qbuf, knope, kpe, vT, out, OloB, mlLo, mlHi);
    attn_combine<<<4096, 256, 0, stream>>>(OloB, mlLo, mlHi, out);
}

// Round 10
// 278.637 us; speedup vs baseline: 1.0428x; 1.0428x over previous
//
#include <hip/hip_runtime.h>

typedef __attribute__((ext_vector_type(8))) short short8;
typedef __attribute__((ext_vector_type(4))) float f32x4;

#define SS 2048
#define HH 16
#define NOPE_D 128
#define ROPE_D 64
#define VDIM 128
#define QD 192
#define SCALE_F 0.07216878364870323f       // 1/sqrt(192)
#define LOG2E 1.4426950408889634f

__device__ __forceinline__ unsigned short f2bf(float f) {
    unsigned int x = __builtin_bit_cast(unsigned int, f);
    unsigned int r = (x + 0x7fffu + ((x >> 16) & 1u)) >> 16;
    return (unsigned short)r;
}
__device__ __forceinline__ float bf2f(unsigned short u) {
    return __builtin_bit_cast(float, (unsigned int)u << 16);
}

#define GLDS16(g, l) __builtin_amdgcn_global_load_lds( \
    (const __attribute__((address_space(1))) void*)(g), \
    (__attribute__((address_space(3))) void*)(l), 16, 0, 0)

// ------- fused f32->bf16 convert (4 arrays) + rope_k, one launch -------
__global__ __launch_bounds__(256) void cvt_all(
    const float* __restrict__ Q, const float* __restrict__ WUQ,
    const float* __restrict__ KV, const float* __restrict__ WUKV,
    const float* __restrict__ PE, const float* __restrict__ cs, const float* __restrict__ sn,
    unsigned short* __restrict__ Qb, unsigned short* __restrict__ WUQb,
    unsigned short* __restrict__ KVb, unsigned short* __restrict__ WUKVb,
    unsigned short* __restrict__ kpe)
{
    int bid = blockIdx.x;
    if (bid >= 14848) {   // rope_k: PE (4096x64) -> kpe bf16
        int idx = (bid - 14848) * 256 + threadIdx.x;
        int i = idx & 31, row = idx >> 5;
        float x1 = PE[row * 64 + i], x2 = PE[row * 64 + 32 + i];
        float c1 = cs[row * 64 + i],      s1 = sn[row * 64 + i];
        float c2 = cs[row * 64 + 32 + i], s2 = sn[row * 64 + 32 + i];
        kpe[row * 64 + i]      = f2bf(x1 * c1 - x2 * s1);
        kpe[row * 64 + 32 + i] = f2bf(x2 * c2 + x1 * s2);
        return;
    }
    const float* src; unsigned short* dst; float scale = 1.0f;
    if (bid < 6144)       { src = Q;    dst = Qb; }
    else if (bid < 10752) { src = WUQ;  dst = WUQb; bid -= 6144; scale = SCALE_F * LOG2E; }
    else if (bid < 12800) { src = KV;   dst = KVb;  bid -= 10752; }
    else                  { src = WUKV; dst = WUKVb; bid -= 12800; }
    int i = (bid * 256 + threadIdx.x) * 4;
    float4 v = *(const float4*)(src + i);
    ushort4 o = { f2bf(v.x * scale), f2bf(v.y * scale), f2bf(v.z * scale), f2bf(v.w * scale) };
    *(ushort4*)(dst + i) = o;
}

// ------- fused GEMM1+GEMM2, 128x128 tile, BK=64, XOR-swizzled LDS -------
__global__ __launch_bounds__(256) void gemm_fused(
    const unsigned short* __restrict__ Qb, const unsigned short* __restrict__ WUQb,
    const unsigned short* __restrict__ KVb, const unsigned short* __restrict__ WUKVb,
    unsigned short* __restrict__ qbuf, unsigned short* __restrict__ knope,
    unsigned short* __restrict__ vT,
    const float* __restrict__ cs, const float* __restrict__ sn)
{
    __shared__ unsigned short As[128 * 64];
    __shared__ unsigned short Bs[128 * 64];
    const int t = threadIdx.x, w = t >> 6, lane = t & 63;
    const int n16 = lane & 15, quad = lane >> 4;

    int bid = blockIdx.x;
    const unsigned short *A, *B; int N, K, bm, bn; bool g1;
    if (bid < 768) { g1 = true;  A = Qb;  B = WUQb;  N = 3072; K = 1536;
                     bm = (bid / 24) * 128; bn = (bid % 24) * 128; }
    else           { g1 = false; bid -= 768; A = KVb; B = WUKVb; N = 4096; K = 512;
                     bm = (bid / 32) * 128; bn = (bid % 32) * 128; }

    const int wm = (w >> 1) * 64, wn = (w & 1) * 64;
    f32x4 acc[4][4] = {};

    const int lr = lane >> 3, lc = lane & 7;
    const int sw = (lc ^ lr) * 8;           // swizzled source chunk
    const unsigned short* gA = A + (size_t)(bm + w * 32 + lr) * K + sw;
    const unsigned short* gB = B + (size_t)(bn + w * 32 + lr) * K + sw;

    for (int k0 = 0; k0 < K; k0 += 64) {
        __syncthreads();
        for (int j = 0; j < 4; j++) {
            GLDS16(gA + (size_t)j * 8 * K + k0, &As[(w * 32 + j * 8) * 64]);
            GLDS16(gB + (size_t)j * 8 * K + k0, &Bs[(w * 32 + j * 8) * 64]);
        }
        __syncthreads();
        for (int ks = 0; ks < 2; ks++) {
            short8 af[4], bf[4];
            for (int mt = 0; mt < 4; mt++) {
                int rw = wm + mt * 16 + n16;
                af[mt] = *(const short8*)&As[rw * 64 + (((ks * 4 + quad) ^ (rw & 7)) * 8)];
            }
            for (int nt = 0; nt < 4; nt++) {
                int rw = wn + nt * 16 + n16;
                bf[nt] = *(const short8*)&Bs[rw * 64 + (((ks * 4 + quad) ^ (rw & 7)) * 8)];
            }
            for (int mt = 0; mt < 4; mt++)
                for (int nt = 0; nt < 4; nt++)
                    acc[mt][nt] = __builtin_amdgcn_mfma_f32_16x16x32_bf16(af[mt], bf[nt], acc[mt][nt], 0, 0, 0);
        }
    }

    const int colbase = bn + wn;
    if (g1) {
        const bool is_pe = ((colbase % 192) >= 128);
        if (is_pe) {
            for (int mt = 0; mt < 4; mt++)
                for (int r = 0; r < 4; r++) {
                    int row = bm + wm + mt * 16 + quad * 4 + r;
                    const float* cr = cs + row * 64;
                    const float* sr = sn + row * 64;
                    for (int nt = 0; nt < 2; nt++) {
                        int i = nt * 16 + n16;
                        float x1 = acc[mt][nt][r], x2 = acc[mt][nt + 2][r];
                        float o1 = x1 * cr[i] - x2 * sr[i];
                        float o2 = x2 * cr[32 + i] + x1 * sr[32 + i];
                        qbuf[(size_t)row * N + colbase + i] = f2bf(o1);
                        qbuf[(size_t)row * N + colbase + 32 + i] = f2bf(o2);
                    }
                }
        } else {
            for (int mt = 0; mt < 4; mt++)
                for (int nt = 0; nt < 4; nt++)
                    for (int r = 0; r < 4; r++)
                        qbuf[(size_t)(bm + wm + mt * 16 + quad * 4 + r) * N + colbase + nt * 16 + n16]
                            = f2bf(acc[mt][nt][r]);
        }
    } else {
        if ((colbase & 255) < 128) {
            for (int mt = 0; mt < 4; mt++)
                for (int nt = 0; nt < 4; nt++) {
                    int col = colbase + nt * 16 + n16;
                    int h = col >> 8, d = col & 255;
                    for (int r = 0; r < 4; r++)
                        knope[(size_t)(bm + wm + mt * 16 + quad * 4 + r) * 2048 + h * 128 + d]
                            = f2bf(acc[mt][nt][r]);
                }
        } else {
            for (int mt = 0; mt < 4; mt++)
                for (int nt = 0; nt < 4; nt++) {
                    int col = colbase + nt * 16 + n16;
                    int h = col >> 8, vd = (col & 255) - 128;
                    int row0 = bm + wm + mt * 16 + quad * 4;
                    int b = row0 >> 11, s0 = row0 & 2047;
                    // key permutation pi within 64-groups (PV A/B pairing order)
                    int l6 = s0 & 63;
                    int scol = (s0 & ~63) + ((l6 >> 5) & 1) * 32 + ((l6 >> 2) & 3) * 8
                             + ((l6 >> 4) & 1) * 4 + (l6 & 3);
                    ushort4 pk = { f2bf(acc[mt][nt][0]), f2bf(acc[mt][nt][1]),
                                   f2bf(acc[mt][nt][2]), f2bf(acc[mt][nt][3]) };
                    *(ushort4*)&vT[((size_t)(b * 16 + h) * 128 + vd) * 2048 + scol] = pk;
                }
        }
    }
}

// ------- flash attention, split-K partial pass -------
// v11 = R8's proven config (QBLK=128, 512 blocks, 2/CU, equal 17-tile spans;
// best total 280.4us) + T5 s_setprio(1) around the MFMA clusters.
// Mechanism (m191): the 2 co-resident blocks per CU drift out of phase;
// priority keeps the MFMA-issuing block's waves fed while the other block's
// waves issue global_load_lds. (QBLK=256 regressed: grid 256 = 1 block/CU
// exposed every stage drain. Pipeline variants R1/R2/R4/R7 all regressed.)
__global__ __launch_bounds__(256, 2) void attn_part(
    const unsigned short* __restrict__ qbuf,   // (4096, 3072) roped, pre-scaled
    const unsigned short* __restrict__ knope,  // (4096, 2048): [row][h*128+d]
    const unsigned short* __restrict__ kpe,    // (4096, 64) roped
    const unsigned short* __restrict__ vT,     // [(b*16+h)*128+vd][pi(s)]
    float* __restrict__ out,                   // (B,S,H,128) f32 (raw hi partial)
    unsigned short* __restrict__ OloB,         // [512][128][128] bf16 lo partial
    float2* __restrict__ mlLo,                 // [512][128] {m,l} lo
    float2* __restrict__ mlHi)                 // [512][128] {m,l} hi
{
    const int t = threadIdx.x, w = t >> 6, lane = t & 63;
    const int n16 = lane & 15, quad = lane >> 4;

    __shared__ unsigned short Kn[64 * 128];
    __shared__ unsigned short Kp[64 * 64];
    __shared__ unsigned short Vt[128 * 64];
    __shared__ float Al[4][32];

    const int j = blockIdx.x;
    const int qtA = j >> 5, cc = j & 31;
    const int h = cc & 15, b = cc >> 4;

    const unsigned short* knb = knope + (size_t)b * 2048 * 2048 + h * 128;
    const unsigned short* kpb = kpe + (size_t)b * 2048 * 64;
    const unsigned short* vtb = vT + (size_t)(b * 16 + h) * 128 * 2048;

    for (int seg = 0; seg < 2; ++seg) {
        const int qt    = seg ? (15 - qtA) : qtA;
        const int ktbeg = seg ? (qt + 1)   : 0;
        const int ktend = seg ? (2 * qt + 2) : (qt + 1);
        const int uid   = qt * 32 + cc;

        // Q as B-frags: wave w covers q rows qt*128 + w*32 + qg*16 + n16
        short8 qf[2][6];
        for (int qg = 0; qg < 2; qg++) {
            size_t grow = (size_t)(b * SS + qt * 128 + w * 32 + qg * 16 + n16);
            const unsigned short* qp = qbuf + grow * (HH * QD) + h * QD + quad * 8;
            for (int ks = 0; ks < 6; ks++) qf[qg][ks] = *(const short8*)(qp + ks * 32);
        }

        f32x4 O[2][8] = {};
        float m_i[2] = { -INFINITY, -INFINITY };
        float l_i[2] = { 0.f, 0.f };

        for (int kt = ktbeg; kt < ktend; kt++) {
            __syncthreads();
            {   // K nope: 64 keys x 128 shorts; 4 glds x 4 rows, XOR swizzle
                int r = w * 16 + (lane >> 4);
                int sl = lane & 15;
                for (int jj = 0; jj < 4; jj++) {
                    int rr = r + jj * 4;
                    const unsigned short* g = knb + (size_t)(kt * 64 + rr) * 2048 + ((sl ^ (rr & 7)) * 8);
                    GLDS16(g, &Kn[(w * 16 + jj * 4) * 128]);
                }
            }
            {   // K pe: 64 keys x 64 shorts; 2 glds x 8 rows
                int r = w * 16 + (lane >> 3);
                int sl = lane & 7;
                for (int jj = 0; jj < 2; jj++) {
                    int rr = r + jj * 8;
                    const unsigned short* g = kpb + (size_t)(kt * 64 + rr) * 64 + ((sl ^ (rr & 7)) * 8);
                    GLDS16(g, &Kp[(w * 16 + jj * 8) * 64]);
                }
            }
            {   // V^T: 128 vd x 64 keys (key-permuted); 4 glds x 8 rows
                int r = w * 32 + (lane >> 3);
                int sl = lane & 7;
                for (int jj = 0; jj < 4; jj++) {
                    int rr = r + jj * 8;
                    const unsigned short* g = vtb + (size_t)rr * 2048 + kt * 64 + ((sl ^ (rr & 7)) * 8);
                    GLDS16(g, &Vt[(w * 32 + jj * 8) * 64]);
                }
            }
            __syncthreads();

            // S^T[key][q]: A = K-frags (LDS, shared across qg), B = Q (regs)
            f32x4 Sg[2][4];
            __builtin_amdgcn_s_setprio(1);
            for (int nt = 0; nt < 4; nt++) {
                int key = nt * 16 + n16, kx = key & 7;
                f32x4 a0 = {}, a1 = {};
                for (int ks = 0; ks < 4; ks++) {
                    short8 af = *(const short8*)&Kn[key * 128 + (((ks * 4 + quad) ^ kx) * 8)];
                    a0 = __builtin_amdgcn_mfma_f32_16x16x32_bf16(af, qf[0][ks], a0, 0, 0, 0);
                    a1 = __builtin_amdgcn_mfma_f32_16x16x32_bf16(af, qf[1][ks], a1, 0, 0, 0);
                }
                for (int ks = 0; ks < 2; ks++) {
                    short8 af = *(const short8*)&Kp[key * 64 + (((ks * 4 + quad) ^ kx) * 8)];
                    a0 = __builtin_amdgcn_mfma_f32_16x16x32_bf16(af, qf[0][4 + ks], a0, 0, 0, 0);
                    a1 = __builtin_amdgcn_mfma_f32_16x16x32_bf16(af, qf[1][4 + ks], a1, 0, 0, 0);
                }
                Sg[0][nt] = a0; Sg[1][nt] = a1;
            }
            __builtin_amdgcn_s_setprio(0);

            if (kt >= 2 * qt) {   // causal mask (only reachable in hi halves & qt=0)
                for (int qg = 0; qg < 2; qg++) {
                    int qq = qt * 128 + w * 32 + qg * 16 + n16;
                    for (int nt = 0; nt < 4; nt++) {
                        int key0 = kt * 64 + nt * 16 + quad * 4;
                        for (int r = 0; r < 4; r++)
                            if (key0 + r > qq) Sg[qg][nt][r] = -INFINITY;
                    }
                }
            }

            // online softmax (base 2), T13 defer-max, msub guard for dead rows
            float alpha[2];
            bool skipq[2];
            for (int qg = 0; qg < 2; qg++) {
                float mx = -INFINITY;
                for (int nt = 0; nt < 4; nt++)
                    for (int r = 0; r < 4; r++) mx = fmaxf(mx, Sg[qg][nt][r]);
                mx = fmaxf(mx, __shfl_xor(mx, 16, 64));
                mx = fmaxf(mx, __shfl_xor(mx, 32, 64));
                const bool skip = __all(mx <= m_i[qg] + 8.0f);
                skipq[qg] = skip;
                float mnew = skip ? m_i[qg] : fmaxf(m_i[qg], mx);
                alpha[qg] = skip ? 1.0f : exp2f(m_i[qg] - mnew);
                m_i[qg] = mnew;
                // msub: if row still has no finite max (fully-masked so far),
                // use 0 so exp2f(-INF - 0) = 0 instead of NaN.
                const float msub = (mnew == -INFINITY) ? 0.0f : mnew;
                float rs = 0.f;
                for (int nt = 0; nt < 4; nt++)
                    for (int r = 0; r < 4; r++) {
                        float pv = exp2f(Sg[qg][nt][r] - msub);
                        Sg[qg][nt][r] = pv;
                        rs += pv;
                    }
                l_i[qg] = l_i[qg] * alpha[qg] + rs;   // per-lane partial (quad-split)
            }
            // broadcast alpha (S^T q=n16 domain) to O lanes (q=quad*4+r domain)
            if (quad == 0) { Al[w][n16] = alpha[0]; Al[w][16 + n16] = alpha[1]; }
            if (!skipq[0]) {
                f32x4 av0 = *(const f32x4*)&Al[w][quad * 4];
                for (int v8 = 0; v8 < 8; v8++)
                    for (int r = 0; r < 4; r++) O[0][v8][r] *= av0[r];
            }
            if (!skipq[1]) {
                f32x4 av1 = *(const f32x4*)&Al[w][16 + quad * 4];
                for (int v8 = 0; v8 < 8; v8++)
                    for (int r = 0; r < 4; r++) O[1][v8][r] *= av1[r];
            }

            // pack P to bf16 A-frags (k order matches pi-permuted V columns)
            short8 pp[2][2];
            for (int qg = 0; qg < 2; qg++)
                for (int ntp = 0; ntp < 2; ntp++) {
                    short8 pa;
                    for (int jj = 0; jj < 4; jj++) pa[jj] = (short)f2bf(Sg[qg][ntp * 2][jj]);
                    for (int jj = 0; jj < 4; jj++) pa[4 + jj] = (short)f2bf(Sg[qg][ntp * 2 + 1][jj]);
                    pp[qg][ntp] = pa;
                }
            // PV: O[q][vd] += P * V, B-frags shared across qg
            __builtin_amdgcn_s_setprio(1);
            for (int ntp = 0; ntp < 2; ntp++)
                for (int v8 = 0; v8 < 8; v8++) {
                    int vd = v8 * 16 + n16;
                    short8 vb = *(const short8*)&Vt[vd * 64 + (((ntp * 4 + quad) ^ (vd & 7)) * 8)];
                    O[0][v8] = __builtin_amdgcn_mfma_f32_16x16x32_bf16(pp[0][ntp], vb, O[0][v8], 0, 0, 0);
                    O[1][v8] = __builtin_amdgcn_mfma_f32_16x16x32_bf16(pp[1][ntp], vb, O[1][v8], 0, 0, 0);
                }
            __builtin_amdgcn_s_setprio(0);
        }

        // epilogue: total l per row (reduce across quads); store RAW partials
        float l0 = l_i[0];
        l0 += __shfl_xor(l0, 16, 64); l0 += __shfl_xor(l0, 32, 64);
        float l1 = l_i[1];
        l1 += __shfl_xor(l1, 16, 64); l1 += __shfl_xor(l1, 32, 64);

        if (seg == 0) {
            unsigned short* lb = OloB + (size_t)uid * 128 * 128;
            for (int qg = 0; qg < 2; qg++)
                for (int r = 0; r < 4; r++) {
                    int row = w * 32 + qg * 16 + quad * 4 + r;
                    unsigned short* lp = lb + (size_t)row * 128;
                    for (int v8 = 0; v8 < 8; v8++)
                        lp[v8 * 16 + n16] = f2bf(O[qg][v8][r]);
                }
            if (quad == 0) {
                mlLo[uid * 128 + w * 32 + n16]      = make_float2(m_i[0], l0);
                mlLo[uid * 128 + w * 32 + 16 + n16] = make_float2(m_i[1], l1);
            }
        } else {
            for (int qg = 0; qg < 2; qg++)
                for (int r = 0; r < 4; r++) {
                    size_t qrow = (size_t)(b * SS + qt * 128 + w * 32 + qg * 16 + quad * 4 + r);
                    float* op = out + (qrow * HH + h) * VDIM;
                    for (int v8 = 0; v8 < 8; v8++)
                        op[v8 * 16 + n16] = O[qg][v8][r];
                }
            if (quad == 0) {
                mlHi[uid * 128 + w * 32 + n16]      = make_float2(m_i[0], l0);
                mlHi[uid * 128 + w * 32 + 16 + n16] = make_float2(m_i[1], l1);
            }
        }
    }
}

// ------- combine: out = (a_lo*O_lo + a_hi*O_hi) / (a_lo*l_lo + a_hi*l_hi) ----
__global__ __launch_bounds__(256) void attn_combine(
    const unsigned short* __restrict__ OloB,
    const float2* __restrict__ mlLo, const float2* __restrict__ mlHi,
    float* __restrict__ out)
{
    int idx = blockIdx.x * 256 + threadIdx.x;   // 512*128*16 threads, 8 vd each
    int vd8 = idx & 15;
    int rowg = idx >> 4;                         // uid*128 + row
    int uid = rowg >> 7, row = rowg & 127;
    int qt = uid >> 5, cc = uid & 31, h = cc & 15, b = cc >> 4;

    float2 lo = mlLo[rowg], hi = mlHi[rowg];
    float m  = fmaxf(lo.x, hi.x);                 // lo.x always finite
    float al = exp2f(lo.x - m);
    float ah = exp2f(hi.x - m);                   // hi.x=-INF -> 0, no NaN
    float rl = 1.f / (lo.y * al + hi.y * ah);
    al *= rl; ah *= rl;

    const unsigned short* lp = OloB + (size_t)rowg * 128 + vd8 * 8;
    float* op = out + ((size_t)(b * SS + qt * 128 + row) * HH + h) * VDIM + vd8 * 8;

    ushort4 u0 = *(const ushort4*)lp;
    ushort4 u1 = *(const ushort4*)(lp + 4);
    float4 h0 = *(const float4*)op;
    float4 h1 = *(const float4*)(op + 4);
    float4 o0, o1;
    o0.x = bf2f(u0.x) * al + h0.x * ah;
    o0.y = bf2f(u0.y) * al + h0.y * ah;
    o0.z = bf2f(u0.z) * al + h0.z * ah;
    o0.w = bf2f(u0.w) * al + h0.w * ah;
    o1.x = bf2f(u1.x) * al + h1.x * ah;
    o1.y = bf2f(u1.y) * al + h1.y * ah;
    o1.z = bf2f(u1.z) * al + h1.z * ah;
    o1.w = bf2f(u1.w) * al + h1.w * ah;
    *(float4*)op = o0;
    *(float4*)(op + 4) = o1;
}

extern "C" void kernel_launch(void* const* d_in, const int* in_sizes, int n_in,
                              void* d_out, int out_size, void* d_ws, size_t ws_size,
                              hipStream_t stream) {
    const float* Q    = (const float*)d_in[0];
    const float* KV   = (const float*)d_in[1];
    const float* PE   = (const float*)d_in[2];
    const float* WUQ  = (const float*)d_in[3];
    const float* WUKV = (const float*)d_in[4];
    const float* cosp = (const float*)d_in[5];
    const float* sinp = (const float*)d_in[6];
    float* out = (float*)d_out;

    unsigned short* qbuf  = (unsigned short*)d_ws;                 // 4096x3072
    unsigned short* knope = qbuf  + (size_t)4096 * 3072;           // 4096x2048
    unsigned short* vT    = knope + (size_t)4096 * 2048;           // 4096x2048 (pi-permuted)
    unsigned short* kpe   = vT    + (size_t)4096 * 2048;           // 4096x64
    unsigned short* Qb    = kpe   + (size_t)4096 * 64;             // 4096x1536
    unsigned short* WUQb  = Qb    + (size_t)4096 * 1536;           // 3072x1536
    unsigned short* KVb   = WUQb  + (size_t)3072 * 1536;           // 4096x512
    unsigned short* WUKVb = KVb   + (size_t)4096 * 512;            // 4096x512

    // split-K partial buffers, overlaid on regions dead after gemm_fused:
    unsigned short* OloB = Qb;                 // 512*128*128 bf16 = 16.8 MB (<= Qb+WUQb)
    float2* mlLo = (float2*)KVb;               // 512*128*8B = 0.5 MB
    float2* mlHi = (float2*)WUKVb;             // 512*128*8B = 0.5 MB

    cvt_all<<<15360, 256, 0, stream>>>(Q, WUQ, KV, WUKV, PE, cosp, sinp,
                                       Qb, WUQb, KVb, WUKVb, kpe);
    gemm_fused<<<1792, 256, 0, stream>>>(Qb, WUQb, KVb, WUKVb,
                                         qbuf, knope, vT, cosp, sinp);
    attn_part<<<512, 256, 0, stream>>>(qbuf, knope, kpe, vT, out, OloB, mlLo, mlHi);
    attn_combine<<<4096, 256, 0, stream>>>(OloB, mlLo, mlHi, out);
}